// Round 6
// baseline (962.351 us; speedup 1.0000x reference)
//
#include <hip/hip_runtime.h>
#include <math.h>

// Problem: B=4, S=4096, D=1024, A=1024, fp32 in/out. No 1/sqrt(d) scaling.
// Strategy: split-bf16 (Ootomo) MFMA: C = Ahi@Bhi + Alo@Bhi + Ahi@Blo.
// All GEMMs NT (A row-major [M,K], B row-major [N,K]) so both operands
// stage via global_load_lds.
// R1: scores -> 256x256 8-phase counted-vmcnt kernel (98us, MfmaUtil 44%).
// R2: merged 128² QKV + splitK PV.  R3: all GEMMs on 8-phase 256².
// R4: uniform-NT qk/v split (qk 101us @44%).
// R5: XCD 2D swizzle (FETCH 203->74MB, dur UNCHANGED -> schedule-internal),
//     batched PV splitK=2 + add2, float4 softmax.
// R6 (this): one-phase-ahead ds_read prefetch inside KITER256 — issue
//   ph2's A-frag reads inside MFMA1's region and ph3/4's inside MFMA2's
//   (cycle model: exposed LDS reads serialize with MFMA -> 45% predicted,
//   44% measured; overlap recovers ~25-35%). sched_barrier(0) pins loads
//   before the MFMA cluster; auto-waitcnt provides precise counted lgkm.
constexpr int CS = 4096;
constexpr int CD = 1024;
constexpr int CA = 1024;
constexpr int CB_ = 4;

typedef unsigned short u16;
typedef __bf16 bf16x8 __attribute__((ext_vector_type(8)));
typedef float f32x4 __attribute__((ext_vector_type(4)));
typedef unsigned short u16x4 __attribute__((ext_vector_type(4)));

__device__ __forceinline__ u16 f32_to_bf16(float f) {
  unsigned u = __float_as_uint(f);
  u = (u + 0x7FFF + ((u >> 16) & 1)) >> 16;  // RNE
  return (u16)u;
}
__device__ __forceinline__ float bf16_to_f32(u16 h) {
  return __uint_as_float(((unsigned)h) << 16);
}

// async global->LDS, 16 B per lane; lds base MUST be wave-uniform.
__device__ __forceinline__ void async16(const u16* g, u16* lds_uniform) {
  __builtin_amdgcn_global_load_lds(
      (const __attribute__((address_space(1))) void*)g,
      (__attribute__((address_space(3))) void*)lds_uniform, 16, 0, 0);
}

// Bijective 2D-chunk XCD swizzle: XCD x (= lin%8) gets a cw x ch tile chunk.
// cw==0 -> identity. Requires GX%cw==0, (GX/cw)*(GY/ch)==8 (host-checked).
__device__ __forceinline__ void xcd_swz(int cw, int ch, int& bx, int& by) {
  if (cw == 0) return;
  const int GX = gridDim.x;
  const int lin = bx + GX * by;
  const int xcd = lin & 7, j = lin >> 3;
  const int ncx = GX / cw;
  bx = (xcd % ncx) * cw + (j % cw);
  by = (xcd / ncx) * ch + (j / cw);
}

// ---------------------------------------------------------------------------
// Shared 256x256 8-phase machinery (guide §5 256² template, plain HIP).
// 512 thr = 8 waves (2M x 4N), BK=64, 128 KiB LDS double-buffered,
// st_16x32 swizzle (inverse-swizzled global src + swizzled ds_read),
// counted vmcnt(6) (never 0 in main loop), s_setprio(1) around MFMA.
// LDS u16 layout: [buf:2][unit:4 = Blo,Bhi,Alo,Ahi][subtile:16][512].
// Per K-tile, 4 phases; A-frag reads for phase p+1 are issued inside phase
// p's MFMA region (prefetch), pinned by sched_barrier(0). Region-death:
// B units die end of ph1; A reads all complete by ph3's lgkm0 (A47 issued
// in ph2's region), before ph4's A-lo stage. Stages in flight during ph1's
// MFMA region target buf^1 only -> prefetch reads of buf are hazard-free.
// Macros reference per-kernel locals: lds, roA, roB, si0, lda, ldb, nbase,
// wr, wc, foff, acc, a1p, a2p, b2p.
// ---------------------------------------------------------------------------
#define ST_A256(BUF, AP, HALF)                                       \
  do {                                                               \
    const u16* _p = (AP) + roA + ((HALF) ? 128L * lda : 0L);         \
    u16* _d = &lds[(BUF)*32768 + (2 + (HALF)) * 8192 + si0 * 512];   \
    async16(_p, _d);                                                 \
    async16(_p + 32, _d + 512);                                      \
  } while (0)
#define ST_B256(BUF, BP, HALF)                                       \
  do {                                                               \
    const u16* _p = (BP) + roB + ((HALF) ? 128L * ldb : 0L);         \
    u16* _d = &lds[(BUF)*32768 + (HALF)*8192 + si0 * 512];           \
    async16(_p, _d);                                                 \
    async16(_p + 32, _d + 512);                                      \
  } while (0)

#define KITER256(T, DO_S1, DO_S2, VMW)                                        \
  do {                                                                        \
    const int buf = (T)&1;                                                    \
    const int bo_a = buf * 32768 + (2 + wr) * 8192;                           \
    const int bo_b = buf * 32768 + (wc >> 1) * 8192;                          \
    bf16x8 Bf[4][2], Am01[2][2], Am23[2][2], A47[4][2];                       \
    /* ---- phase 1: read all-B + A m0-1; stage (t+1).A-hi ---- */            \
    _Pragma("unroll") for (int n = 0; n < 4; ++n) _Pragma("unroll")           \
        for (int kk = 0; kk < 2; ++kk) Bf[n][kk] =                            \
        *(const bf16x8*)&lds[bo_b + ((nbase + n) * 2 + kk) * 512 + foff];     \
    _Pragma("unroll") for (int m = 0; m < 2; ++m) _Pragma("unroll")           \
        for (int kk = 0; kk < 2; ++kk) Am01[m][kk] =                          \
        *(const bf16x8*)&lds[bo_a + (m * 2 + kk) * 512 + foff];               \
    if (DO_S1) ST_A256(buf ^ 1, a1p, 1);                                      \
    __builtin_amdgcn_s_barrier();                                             \
    asm volatile("s_waitcnt lgkmcnt(0)" ::: "memory");                        \
    /* prefetch ph2's A m2-3 under MFMA1 */                                   \
    _Pragma("unroll") for (int m = 0; m < 2; ++m) _Pragma("unroll")           \
        for (int kk = 0; kk < 2; ++kk) Am23[m][kk] =                          \
        *(const bf16x8*)&lds[bo_a + ((2 + m) * 2 + kk) * 512 + foff];         \
    __builtin_amdgcn_sched_barrier(0);                                        \
    __builtin_amdgcn_s_setprio(1);                                            \
    _Pragma("unroll") for (int m = 0; m < 2; ++m) _Pragma("unroll")           \
        for (int n = 0; n < 4; ++n) _Pragma("unroll")                         \
        for (int kk = 0; kk < 2; ++kk) acc[m][n] =                            \
        __builtin_amdgcn_mfma_f32_16x16x32_bf16(Am01[m][kk], Bf[n][kk],       \
                                                acc[m][n], 0, 0, 0);          \
    __builtin_amdgcn_s_setprio(0);                                            \
    __builtin_amdgcn_s_barrier();                                             \
    /* ---- phase 2: stage (t+2).B-lo; MFMA m2-3 ---- */                      \
    if (DO_S2) ST_B256(buf, b2p, 0);                                          \
    __builtin_amdgcn_s_barrier();                                             \
    asm volatile("s_waitcnt lgkmcnt(0)" ::: "memory");                        \
    /* prefetch ph3/4's A m4-7 under MFMA2 */                                 \
    _Pragma("unroll") for (int m = 0; m < 4; ++m) _Pragma("unroll")           \
        for (int kk = 0; kk < 2; ++kk) A47[m][kk] =                           \
        *(const bf16x8*)&lds[bo_a + ((4 + m) * 2 + kk) * 512 + foff];         \
    __builtin_amdgcn_sched_barrier(0);                                        \
    __builtin_amdgcn_s_setprio(1);                                            \
    _Pragma("unroll") for (int m = 0; m < 2; ++m) _Pragma("unroll")           \
        for (int n = 0; n < 4; ++n) _Pragma("unroll")                         \
        for (int kk = 0; kk < 2; ++kk) acc[2 + m][n] =                        \
        __builtin_amdgcn_mfma_f32_16x16x32_bf16(Am23[m][kk], Bf[n][kk],       \
                                                acc[2 + m][n], 0, 0, 0);      \
    __builtin_amdgcn_s_setprio(0);                                            \
    __builtin_amdgcn_s_barrier();                                             \
    /* ---- phase 3: stage (t+2).B-hi; MFMA m4-5 ---- */                      \
    if (DO_S2) ST_B256(buf, b2p, 1);                                          \
    __builtin_amdgcn_s_barrier();                                             \
    asm volatile("s_waitcnt lgkmcnt(0)" ::: "memory");                        \
    __builtin_amdgcn_s_setprio(1);                                            \
    _Pragma("unroll") for (int m = 0; m < 2; ++m) _Pragma("unroll")           \
        for (int n = 0; n < 4; ++n) _Pragma("unroll")                         \
        for (int kk = 0; kk < 2; ++kk) acc[4 + m][n] =                        \
        __builtin_amdgcn_mfma_f32_16x16x32_bf16(A47[m][kk], Bf[n][kk],        \
                                                acc[4 + m][n], 0, 0, 0);      \
    __builtin_amdgcn_s_setprio(0);                                            \
    __builtin_amdgcn_s_barrier();                                             \
    /* ---- phase 4: stage (t+2).A-lo; MFMA m6-7; counted vmcnt ---- */       \
    if (DO_S2) ST_A256(buf, a2p, 0);                                          \
    __builtin_amdgcn_s_barrier();                                             \
    asm volatile("s_waitcnt lgkmcnt(0)" ::: "memory");                        \
    __builtin_amdgcn_s_setprio(1);                                            \
    _Pragma("unroll") for (int m = 0; m < 2; ++m) _Pragma("unroll")           \
        for (int n = 0; n < 4; ++n) _Pragma("unroll")                         \
        for (int kk = 0; kk < 2; ++kk) acc[6 + m][n] =                        \
        __builtin_amdgcn_mfma_f32_16x16x32_bf16(A47[2 + m][kk], Bf[n][kk],    \
                                                acc[6 + m][n], 0, 0, 0);      \
    __builtin_amdgcn_s_setprio(0);                                            \
    VMW;                                                                      \
    __builtin_amdgcn_s_barrier();                                             \
  } while (0)

// ---------------------------------------------------------------------------
// Scores GEMM: generic NSEG-segmented NT, fp32 C out.
// ---------------------------------------------------------------------------
template <int NSEG>
__global__ __launch_bounds__(512, 2) void gemm256_nt(
    const u16* __restrict__ A0s, const u16* __restrict__ A1s,
    const u16* __restrict__ A2s, const u16* __restrict__ B0s,
    const u16* __restrict__ B1s, const u16* __restrict__ B2s,
    float* __restrict__ C, int Kd, int lda, int ldb, int ldc, int cw,
    int ch) {
  __shared__ u16 lds[65536];  // 128 KiB
  const int tid = threadIdx.x;
  const int wave = tid >> 6, lane = tid & 63;
  const int wr = wave >> 2, wc = wave & 3;       // wave -> 128x64 C sub-tile
  const int l16 = lane & 15, quad = lane >> 4;
  int bx = blockIdx.x, by = blockIdx.y;
  xcd_swz(cw, ch, bx, by);
  const int m0 = by * 256, n0 = bx * 256;
  const int foff = (l16 * 32 + quad * 8) ^ ((l16 & 8) << 1);
  const int si0 = wave * 2;
  const int srow = lane >> 2;                                  // subtile row
  const int scol = ((lane & 3) * 8) ^ ((lane & 32) ? 16 : 0);  // inv-swz col
  const long roA = (long)(m0 + wave * 16 + srow) * lda + scol;
  const long roB = (long)(n0 + wave * 16 + srow) * ldb + scol;
  const int nbase = (wc & 1) * 4;

  f32x4 acc[8][4];
#pragma unroll
  for (int i = 0; i < 8; ++i)
#pragma unroll
    for (int j = 0; j < 4; ++j) acc[i][j] = (f32x4){0.f, 0.f, 0.f, 0.f};

  const int ktps = Kd >> 6;       // K-tiles per segment
  const int NT = NSEG * ktps;     // total K-tiles

  // cursor1 -> K-tile 1
  int s1 = 0, k1 = 64;
  if (k1 == Kd) { k1 = 0; s1 = 1; }
  const u16* a1p = (s1 == 0 ? A0s : A1s) + k1;
  const u16* b1p = (s1 == 0 ? B0s : B1s) + k1;
  // prologue: K-tile 0 {Blo,Bhi,Alo,Ahi}, K-tile 1 {Blo,Bhi,Alo}
  ST_B256(0, B0s, 0);
  ST_B256(0, B0s, 1);
  ST_A256(0, A0s, 0);
  ST_A256(0, A0s, 1);
  ST_B256(1, b1p, 0);
  ST_B256(1, b1p, 1);
  ST_A256(1, a1p, 0);
  (void)b1p;
  // cursor2 -> K-tile 2
  int s2 = s1, k2 = k1 + 64;
  if (k2 == Kd) { k2 = 0; ++s2; }
  const u16* a2p = (s2 == 0 ? A0s : (s2 == 1 ? A1s : A2s)) + k2;
  const u16* b2p = (s2 == 0 ? B0s : (s2 == 1 ? B1s : B2s)) + k2;
  asm volatile("s_waitcnt vmcnt(6)" ::: "memory");  // K-tile 0 resident
  __builtin_amdgcn_s_barrier();

  for (int t = 0; t + 2 < NT; ++t) {
    KITER256(t, 1, 1, asm volatile("s_waitcnt vmcnt(6)" ::: "memory"));
    a1p = a2p;
    k2 += 64;
    if (k2 == Kd) {
      k2 = 0;
      ++s2;
      a2p = (s2 == 1 ? A1s : A2s);
      b2p = (s2 == 1 ? B1s : B2s);
    } else {
      a2p += 64;
      b2p += 64;
    }
  }
  // tails: t = NT-2 stages only (NT-1).A-hi, drains vmcnt; t = NT-1 pure.
  KITER256(NT - 2, 1, 0, asm volatile("s_waitcnt vmcnt(0)" ::: "memory"));
  KITER256(NT - 1, 0, 0, ((void)0));

  // epilogue: fp32 C. frag layout: col = lane&15, row = quad*4 + reg.
  const int rb0 = m0 + wr * 128 + quad * 4;
  const int cc0 = n0 + wc * 64 + l16;
#pragma unroll
  for (int m = 0; m < 8; ++m)
#pragma unroll
    for (int n = 0; n < 4; ++n) {
      const long rb = rb0 + m * 16;
      const int c = cc0 + n * 16;
#pragma unroll
      for (int r = 0; r < 4; ++r) C[(rb + r) * (long)ldc + c] = acc[m][n][r];
    }
}

// ---------------------------------------------------------------------------
// Q/K projection, UNIFORM NT=48 (3 segments). Region by n0>>10: 0=Q, 1=K;
// both split hi/lo out. Grid (8, 16*nb).
// ---------------------------------------------------------------------------
__global__ __launch_bounds__(512, 2) void gemm256_qk(
    const u16* __restrict__ Xhi, const u16* __restrict__ Xlo,
    const u16* __restrict__ Whi, const u16* __restrict__ Wlo,
    u16* __restrict__ Qhi, u16* __restrict__ Qlo, u16* __restrict__ Khi,
    u16* __restrict__ Klo, int cw, int ch) {
  __shared__ u16 lds[65536];
  const int tid = threadIdx.x;
  const int wave = tid >> 6, lane = tid & 63;
  const int wr = wave >> 2, wc = wave & 3;
  const int l16 = lane & 15, quad = lane >> 4;
  int bx = blockIdx.x, by = blockIdx.y;
  xcd_swz(cw, ch, bx, by);
  const int m0 = by * 256, n0 = bx * 256;
  const int region = n0 >> 10;  // 0=Q 1=K
  const int lda = CD, ldb = CD;
  const int foff = (l16 * 32 + quad * 8) ^ ((l16 & 8) << 1);
  const int si0 = wave * 2;
  const int srow = lane >> 2;
  const int scol = ((lane & 3) * 8) ^ ((lane & 32) ? 16 : 0);
  const long roA = (long)(m0 + wave * 16 + srow) * lda + scol;
  const long roB = (long)(n0 + wave * 16 + srow) * ldb + scol;
  const int nbase = (wc & 1) * 4;

  f32x4 acc[8][4];
#pragma unroll
  for (int i = 0; i < 8; ++i)
#pragma unroll
    for (int j = 0; j < 4; ++j) acc[i][j] = (f32x4){0.f, 0.f, 0.f, 0.f};

  const u16* Asegs[3] = {Xhi, Xlo, Xhi};
  const u16* Bsegs[3] = {Whi, Whi, Wlo};
  const int NT = 48;  // 3 segments x 16 K-tiles (Kd=1024, BK=64)

  const u16* a1p = Xhi + 64;
  int s2 = 0, k2 = 128;
  const u16* a2p = Xhi + 128;
  const u16* b2p = Whi + 128;
  ST_B256(0, Whi, 0);
  ST_B256(0, Whi, 1);
  ST_A256(0, Xhi, 0);
  ST_A256(0, Xhi, 1);
  ST_B256(1, Whi + 64, 0);
  ST_B256(1, Whi + 64, 1);
  ST_A256(1, Xhi + 64, 0);
  asm volatile("s_waitcnt vmcnt(6)" ::: "memory");
  __builtin_amdgcn_s_barrier();

  for (int t = 0; t + 2 < NT; ++t) {
    KITER256(t, 1, 1, asm volatile("s_waitcnt vmcnt(6)" ::: "memory"));
    a1p = a2p;
    k2 += 64;
    if (k2 == CD) {
      k2 = 0;
      ++s2;
      if (s2 < 3) {
        a2p = Asegs[s2];
        b2p = Bsegs[s2];
      }
    } else {
      a2p += 64;
      b2p += 64;
    }
  }
  KITER256(NT - 2, 1, 0, asm volatile("s_waitcnt vmcnt(0)" ::: "memory"));
  KITER256(NT - 1, 0, 0, ((void)0));

  // epilogue: col = lane&15, row = quad*4 + reg (m89-verified mapping).
  const int rb0 = m0 + wr * 128 + quad * 4;
  const int ccl = (n0 & 1023) + wc * 64 + l16;
  u16* Chi = region ? Khi : Qhi;
  u16* Clo = region ? Klo : Qlo;
#pragma unroll
  for (int m = 0; m < 8; ++m)
#pragma unroll
    for (int n = 0; n < 4; ++n) {
      const long rb = rb0 + m * 16;
      const int c = ccl + n * 16;
#pragma unroll
      for (int r = 0; r < 4; ++r) {
        const float v = acc[m][n][r];
        const u16 h = f32_to_bf16(v);
        Chi[(rb + r) * (long)CA + c] = h;
        Clo[(rb + r) * (long)CA + c] = f32_to_bf16(v - bf16_to_f32(h));
      }
    }
}

// ---------------------------------------------------------------------------
// V projection, NT=16 (NSEG=1). Transposed bf16 out: Vt[batch][a][s].
// Grid (4, 16*nb).
// ---------------------------------------------------------------------------
__global__ __launch_bounds__(512, 2) void gemm256_v(
    const u16* __restrict__ Xhi, const u16* __restrict__ Wvhi,
    u16* __restrict__ Vt, int cw, int ch) {
  __shared__ u16 lds[65536];
  const int tid = threadIdx.x;
  const int wave = tid >> 6, lane = tid & 63;
  const int wr = wave >> 2, wc = wave & 3;
  const int l16 = lane & 15, quad = lane >> 4;
  int bx = blockIdx.x, by = blockIdx.y;
  xcd_swz(cw, ch, bx, by);
  const int m0 = by * 256, n0 = bx * 256;
  const int lda = CD, ldb = CD;
  const int foff = (l16 * 32 + quad * 8) ^ ((l16 & 8) << 1);
  const int si0 = wave * 2;
  const int srow = lane >> 2;
  const int scol = ((lane & 3) * 8) ^ ((lane & 32) ? 16 : 0);
  const long roA = (long)(m0 + wave * 16 + srow) * lda + scol;
  const long roB = (long)(n0 + wave * 16 + srow) * ldb + scol;
  const int nbase = (wc & 1) * 4;

  f32x4 acc[8][4];
#pragma unroll
  for (int i = 0; i < 8; ++i)
#pragma unroll
    for (int j = 0; j < 4; ++j) acc[i][j] = (f32x4){0.f, 0.f, 0.f, 0.f};

  const int NT = 16;
  const u16* a1p = Xhi + 64;
  const u16* a2p = Xhi + 128;
  const u16* b2p = Wvhi + 128;
  ST_B256(0, Wvhi, 0);
  ST_B256(0, Wvhi, 1);
  ST_A256(0, Xhi, 0);
  ST_A256(0, Xhi, 1);
  ST_B256(1, Wvhi + 64, 0);
  ST_B256(1, Wvhi + 64, 1);
  ST_A256(1, Xhi + 64, 0);
  asm volatile("s_waitcnt vmcnt(6)" ::: "memory");
  __builtin_amdgcn_s_barrier();

  for (int t = 0; t + 2 < NT; ++t) {
    KITER256(t, 1, 1, asm volatile("s_waitcnt vmcnt(6)" ::: "memory"));
    a1p = a2p;
    a2p += 64;
    b2p += 64;
  }
  KITER256(NT - 2, 1, 0, asm volatile("s_waitcnt vmcnt(0)" ::: "memory"));
  KITER256(NT - 1, 0, 0, ((void)0));

  // epilogue: transposed bf16 per batch: Vt[batch][a][s].
  const int rb0 = m0 + wr * 128 + quad * 4;
  const int ccl = n0 + wc * 64 + l16;
#pragma unroll
  for (int m = 0; m < 8; ++m) {
    const int rg = rb0 + m * 16;
    const long vb = (long)(rg >> 12) * CA * CS;
    const int s = rg & 4095;
#pragma unroll
    for (int n = 0; n < 4; ++n) {
      const int c = ccl + n * 16;
      u16x4 p;
#pragma unroll
      for (int r = 0; r < 4; ++r) p[r] = f32_to_bf16(acc[m][n][r]);
      *(u16x4*)&Vt[vb + (long)c * CS + s] = p;
    }
  }
}

// ---------------------------------------------------------------------------
// PV split-K=4 (single batch). Grid (4,16,4). Partials Cp + z*CS*CA.
// ---------------------------------------------------------------------------
__global__ __launch_bounds__(512, 2) void gemm256_pv(
    const u16* __restrict__ P, const u16* __restrict__ Vtb,
    float* __restrict__ Cp, int cw, int ch) {
  __shared__ u16 lds[65536];
  const int tid = threadIdx.x;
  const int wave = tid >> 6, lane = tid & 63;
  const int wr = wave >> 2, wc = wave & 3;
  const int l16 = lane & 15, quad = lane >> 4;
  int bx = blockIdx.x, by = blockIdx.y;
  xcd_swz(cw, ch, bx, by);
  const int m0 = by * 256, n0 = bx * 256;
  const int z = blockIdx.z;
  const int lda = CS, ldb = CS;
  const int foff = (l16 * 32 + quad * 8) ^ ((l16 & 8) << 1);
  const int si0 = wave * 2;
  const int srow = lane >> 2;
  const int scol = ((lane & 3) * 8) ^ ((lane & 32) ? 16 : 0);
  const long roA = (long)(m0 + wave * 16 + srow) * lda + scol;
  const long roB = (long)(n0 + wave * 16 + srow) * ldb + scol;
  const int nbase = (wc & 1) * 4;

  f32x4 acc[8][4];
#pragma unroll
  for (int i = 0; i < 8; ++i)
#pragma unroll
    for (int j = 0; j < 4; ++j) acc[i][j] = (f32x4){0.f, 0.f, 0.f, 0.f};

  const u16* A0 = P + (long)z * 1024;
  const u16* B0 = Vtb + (long)z * 1024;
  const int NT = 16;
  const u16* a1p = A0 + 64;
  const u16* a2p = A0 + 128;
  const u16* b2p = B0 + 128;
  ST_B256(0, B0, 0);
  ST_B256(0, B0, 1);
  ST_A256(0, A0, 0);
  ST_A256(0, A0, 1);
  ST_B256(1, B0 + 64, 0);
  ST_B256(1, B0 + 64, 1);
  ST_A256(1, A0 + 64, 0);
  asm volatile("s_waitcnt vmcnt(6)" ::: "memory");
  __builtin_amdgcn_s_barrier();

  for (int t = 0; t + 2 < NT; ++t) {
    KITER256(t, 1, 1, asm volatile("s_waitcnt vmcnt(6)" ::: "memory"));
    a1p = a2p;
    a2p += 64;
    b2p += 64;
  }
  KITER256(NT - 2, 1, 0, asm volatile("s_waitcnt vmcnt(0)" ::: "memory"));
  KITER256(NT - 1, 0, 0, ((void)0));

  float* C = Cp + (long)z * CS * CA;
  const int rb0 = m0 + wr * 128 + quad * 4;
  const int cc0 = n0 + wc * 64 + l16;
#pragma unroll
  for (int m = 0; m < 8; ++m)
#pragma unroll
    for (int n = 0; n < 4; ++n) {
      const long rb = rb0 + m * 16;
      const int c = cc0 + n * 16;
#pragma unroll
      for (int r = 0; r < 4; ++r) C[(rb + r) * (long)CA + c] = acc[m][n][r];
    }
}

// ---------------------------------------------------------------------------
// Batched PV: 2 batches x split-K=2, NT=32. Grid (4, 32, 2) = 256 blocks.
// P2 = 2 contiguous [CS,CS] bf16 planes; Vt = 2 x [CA,CS]; partials
// Cp[batch*2 + z][CS,CA] fp32. Block row-range never crosses a batch.
// ---------------------------------------------------------------------------
__global__ __launch_bounds__(512, 2) void gemm256_pv2(
    const u16* __restrict__ P2, const u16* __restrict__ Vt,
    float* __restrict__ Cp, int cw, int ch) {
  __shared__ u16 lds[65536];
  const int tid = threadIdx.x;
  const int wave = tid >> 6, lane = tid & 63;
  const int wr = wave >> 2, wc = wave & 3;
  const int l16 = lane & 15, quad = lane >> 4;
  int bx = blockIdx.x, by = blockIdx.y;
  xcd_swz(cw, ch, bx, by);
  const int z = blockIdx.z;
  const int batch = by >> 4;
  const int m0 = (by & 15) * 256, n0 = bx * 256;
  const int lda = CS, ldb = CS;
  const int foff = (l16 * 32 + quad * 8) ^ ((l16 & 8) << 1);
  const int si0 = wave * 2;
  const int srow = lane >> 2;
  const int scol = ((lane & 3) * 8) ^ ((lane & 32) ? 16 : 0);
  const long roA = (long)(m0 + wave * 16 + srow) * lda + scol;
  const long roB = (long)(n0 + wave * 16 + srow) * ldb + scol;
  const int nbase = (wc & 1) * 4;

  f32x4 acc[8][4];
#pragma unroll
  for (int i = 0; i < 8; ++i)
#pragma unroll
    for (int j = 0; j < 4; ++j) acc[i][j] = (f32x4){0.f, 0.f, 0.f, 0.f};

  const u16* A0 = P2 + (long)batch * CS * CS + (long)z * 2048;
  const u16* B0 = Vt + (long)batch * CA * CS + (long)z * 2048;
  const int NT = 32;  // K = 2048 per z
  const u16* a1p = A0 + 64;
  const u16* a2p = A0 + 128;
  const u16* b2p = B0 + 128;
  ST_B256(0, B0, 0);
  ST_B256(0, B0, 1);
  ST_A256(0, A0, 0);
  ST_A256(0, A0, 1);
  ST_B256(1, B0 + 64, 0);
  ST_B256(1, B0 + 64, 1);
  ST_A256(1, A0 + 64, 0);
  asm volatile("s_waitcnt vmcnt(6)" ::: "memory");
  __builtin_amdgcn_s_barrier();

  for (int t = 0; t + 2 < NT; ++t) {
    KITER256(t, 1, 1, asm volatile("s_waitcnt vmcnt(6)" ::: "memory"));
    a1p = a2p;
    a2p += 64;
    b2p += 64;
  }
  KITER256(NT - 2, 1, 0, asm volatile("s_waitcnt vmcnt(0)" ::: "memory"));
  KITER256(NT - 1, 0, 0, ((void)0));

  float* C = Cp + ((long)batch * 2 + z) * CS * CA;
  const int rb0 = m0 + wr * 128 + quad * 4;
  const int cc0 = n0 + wc * 64 + l16;
#pragma unroll
  for (int m = 0; m < 8; ++m)
#pragma unroll
    for (int n = 0; n < 4; ++n) {
      const long rb = rb0 + m * 16;
      const int c = cc0 + n * 16;
#pragma unroll
      for (int r = 0; r < 4; ++r) C[(rb + r) * (long)CA + c] = acc[m][n][r];
    }
}

#undef KITER256
#undef ST_A256
#undef ST_B256

// ---------------------------------------------------------------------------
// Legacy 128² PV (tiny-ws fallback only): direct full-K into C.
// ---------------------------------------------------------------------------
template <int KD>
__global__ __launch_bounds__(256) void gemm_pv(const u16* __restrict__ P,
                                               const u16* __restrict__ Vtb,
                                               float* __restrict__ Cp) {
  __shared__ u16 As[128 * 32];
  __shared__ u16 Bs[128 * 32];
  const int tid = threadIdx.x;
  const int wave = tid >> 6, lane = tid & 63;
  const int quad = lane >> 4, l16 = lane & 15;
  const int m0 = blockIdx.y * 128, n0 = blockIdx.x * 128;
  const int z = blockIdx.z;
  const int wm = (wave >> 1) * 64, wn = (wave & 1) * 64;
  const int srow = lane >> 2;
  const int scol = (lane & 3) * 8;
  const int c0 = wave, c1 = wave + 4;

  const u16* Ab = P + (long)m0 * CS + (long)z * KD;
  const u16* Bb = Vtb + (long)n0 * CS + (long)z * KD;
  float* C = Cp + (long)z * CS * CA;

  f32x4 acc[4][4];
#pragma unroll
  for (int i = 0; i < 4; ++i)
#pragma unroll
    for (int j = 0; j < 4; ++j) acc[i][j] = (f32x4){0.f, 0.f, 0.f, 0.f};

  for (int k0 = 0; k0 < KD; k0 += 32) {
    async16(Ab + (long)(c0 * 16 + srow) * CS + k0 + scol, As + c0 * 512);
    async16(Ab + (long)(c1 * 16 + srow) * CS + k0 + scol, As + c1 * 512);
    async16(Bb + (long)(c0 * 16 + srow) * CS + k0 + scol, Bs + c0 * 512);
    async16(Bb + (long)(c1 * 16 + srow) * CS + k0 + scol, Bs + c1 * 512);
    __syncthreads();
    bf16x8 af[4], bfr[4];
#pragma unroll
    for (int i = 0; i < 4; ++i)
      af[i] = *(const bf16x8*)&As[(wm + i * 16 + l16) * 32 + quad * 8];
#pragma unroll
    for (int j = 0; j < 4; ++j)
      bfr[j] = *(const bf16x8*)&Bs[(wn + j * 16 + l16) * 32 + quad * 8];
#pragma unroll
    for (int i = 0; i < 4; ++i)
#pragma unroll
      for (int j = 0; j < 4; ++j)
        acc[i][j] = __builtin_amdgcn_mfma_f32_16x16x32_bf16(af[i], bfr[j],
                                                            acc[i][j], 0, 0, 0);
    __syncthreads();
  }

#pragma unroll
  for (int i = 0; i < 4; ++i) {
    const int rb = m0 + wm + i * 16 + quad * 4;
#pragma unroll
    for (int j = 0; j < 4; ++j) {
      const int c = n0 + wn + j * 16 + l16;
#pragma unroll
      for (int r = 0; r < 4; ++r) C[(long)(rb + r) * CA + c] = acc[i][j][r];
    }
  }
}

// o = p0+p1+p2+p3 (stride CS*CA floats), float4-vectorized.
__global__ __launch_bounds__(256) void add4_f32(const float* __restrict__ p,
                                                float* __restrict__ o, int n4) {
  const int idx = blockIdx.x * 256 + threadIdx.x;
  if (idx >= n4) return;
  const long st = (long)CS * CA / 4;
  const float4 a = ((const float4*)p)[idx];
  const float4 b = ((const float4*)p)[idx + st];
  const float4 c = ((const float4*)p)[idx + 2 * st];
  const float4 d = ((const float4*)p)[idx + 3 * st];
  float4 r;
  r.x = (a.x + b.x) + (c.x + d.x);
  r.y = (a.y + b.y) + (c.y + d.y);
  r.z = (a.z + b.z) + (c.z + d.z);
  r.w = (a.w + b.w) + (c.w + d.w);
  ((float4*)o)[idx] = r;
}

// o = a + b, float4-vectorized.
__global__ __launch_bounds__(256) void add2_f32(const float* __restrict__ a,
                                                const float* __restrict__ b,
                                                float* __restrict__ o, int n4) {
  const int idx = blockIdx.x * 256 + threadIdx.x;
  if (idx >= n4) return;
  const float4 x = ((const float4*)a)[idx];
  const float4 y = ((const float4*)b)[idx];
  float4 r;
  r.x = x.x + y.x;
  r.y = x.y + y.y;
  r.z = x.z + y.z;
  r.w = x.w + y.w;
  ((float4*)o)[idx] = r;
}

// ---------------------------------------------------------------------------
// W [D,A] fp32 -> Wt hi/lo bf16 [A,D] (transposed). Tlo may be null.
// ---------------------------------------------------------------------------
__global__ __launch_bounds__(256) void wtrans_split(const float* __restrict__ W,
                                                    u16* __restrict__ Thi,
                                                    u16* __restrict__ Tlo) {
  __shared__ float t[32][33];
  const int tx = threadIdx.x & 31, ty = threadIdx.x >> 5;
  const int a0 = blockIdx.x * 32;  // col tile of W (a)
  const int d0 = blockIdx.y * 32;  // row tile of W (d)
#pragma unroll
  for (int i = 0; i < 32; i += 8)
    t[ty + i][tx] = W[(long)(d0 + ty + i) * CA + a0 + tx];
  __syncthreads();
#pragma unroll
  for (int i = 0; i < 32; i += 8) {
    const float v = t[tx][ty + i];  // = W[d0+tx][a0+ty+i]
    const int a = a0 + ty + i, d = d0 + tx;
    const u16 h = f32_to_bf16(v);
    Thi[(long)a * CD + d] = h;
    if (Tlo) Tlo[(long)a * CD + d] = f32_to_bf16(v - bf16_to_f32(h));
  }
}

// fp32 -> (hi, lo) bf16, elementwise, float4-vectorized.
__global__ __launch_bounds__(256) void split_f32(const float* __restrict__ X,
                                                 u16* __restrict__ hi,
                                                 u16* __restrict__ lo, int n4) {
  const int idx = blockIdx.x * 256 + threadIdx.x;
  if (idx >= n4) return;
  const float4 v = ((const float4*)X)[idx];
  u16x4 h, l;
  const float vv[4] = {v.x, v.y, v.z, v.w};
#pragma unroll
  for (int i = 0; i < 4; ++i) {
    h[i] = f32_to_bf16(vv[i]);
    l[i] = f32_to_bf16(vv[i] - bf16_to_f32(h[i]));
  }
  ((u16x4*)hi)[idx] = h;
  ((u16x4*)lo)[idx] = l;
}

// ---------------------------------------------------------------------------
// Row softmax over 4096-wide rows (fp32 in, bf16 out), one block per row,
// float4 loads / u16x4 stores.
// ---------------------------------------------------------------------------
__global__ __launch_bounds__(256) void softmax_bf16(const float* __restrict__ Sc,
                                                    u16* __restrict__ P) {
  const long row = blockIdx.x;
  const float4* p4 = (const float4*)(Sc + row * 4096L);
  u16x4* q4 = (u16x4*)(P + row * 4096L);
  const int tid = threadIdx.x;

  float4 v[4];
#pragma unroll
  for (int i = 0; i < 4; ++i) v[i] = p4[tid + (i << 8)];
  float r[16];
#pragma unroll
  for (int i = 0; i < 4; ++i) {
    r[4 * i] = v[i].x;
    r[4 * i + 1] = v[i].y;
    r[4 * i + 2] = v[i].z;
    r[4 * i + 3] = v[i].w;
  }

  float m = r[0];
#pragma unroll
  for (int i = 1; i < 16; ++i) m = fmaxf(m, r[i]);
#pragma unroll
  for (int off = 32; off > 0; off >>= 1) m = fmaxf(m, __shfl_down(m, off));

  __shared__ float smax[4];
  __shared__ float ssum[4];
  const int lane = tid & 63;
  const int wv = tid >> 6;
  if (lane == 0) smax[wv] = m;
  __syncthreads();
  m = fmaxf(fmaxf(smax[0], smax[1]), fmaxf(smax[2], smax[3]));

  float s = 0.f;
#pragma unroll
  for (int i = 0; i < 16; ++i) {
    r[i] = __expf(r[i] - m);
    s += r[i];
  }
#pragma unroll
  for (int off = 32; off > 0; off >>= 1) s += __shfl_down(s, off);
  if (lane == 0) ssum[wv] = s;
  __syncthreads();
  s = (ssum[0] + ssum[1]) + (ssum[2] + ssum[3]);

  const float inv = 1.0f / s;
#pragma unroll
  for (int i = 0; i < 4; ++i) {
    u16x4 h;
#pragma unroll
    for (int k = 0; k < 4; ++k) h[k] = f32_to_bf16(r[4 * i + k] * inv);
    q4[tid + (i << 8)] = h;
  }
}

// ---------------------------------------------------------------------------
// Workspace layout (byte offsets), batch-group size nb in {4,2,1}:
//  0: Whi [3072,1024] (6 MB), 6: Wlo (Q|K rows, 4 MB)     [resident]
// 10: Qhi/Qlo/Khi/Klo (each 8*nb) , Vt (8*nb)  -> [10, 10+40nb)
// 10+40nb: P (32 MB; 64 MB when bigP: both batches)
// then: Sc (64 MB fp32) ALIASED with X staging and PV partials.
// need: nb=1 -> 146 (proven R1), nb=2 -> 186 (proven R3), nb=2+bigP -> 218
// (proven R5), nb=4 -> 266. Gated on ws_size.
// ---------------------------------------------------------------------------
extern "C" void kernel_launch(void* const* d_in, const int* in_sizes, int n_in,
                              void* d_out, int out_size, void* d_ws,
                              size_t ws_size, hipStream_t stream) {
  const float* X = (const float*)d_in[0];
  const float* Wq = (const float*)d_in[1];
  const float* Wk = (const float*)d_in[2];
  const float* Wv = (const float*)d_in[3];
  float* out = (float*)d_out;

  const size_t MB = 1 << 20;
  char* w = (char*)d_ws;
  u16* Whi = (u16*)(w + 0 * MB);  // [3072,1024] Q|K|V hi
  u16* Wlo = (u16*)(w + 6 * MB);  // [2048,1024] Q|K lo

  int nb = 1;
  if (ws_size >= 266 * MB) nb = 4;
  else if (ws_size >= 186 * MB) nb = 2;
  const bool big = ws_size >= 146 * MB;
  if (!big) nb = 1;
  const bool bigP = (nb == 2) && (ws_size >= 218 * MB);  // batched PV path

  const size_t bs = (size_t)CS * CA * 2;  // 8 MB: one bf16 [4096,1024] plane
  u16* Qhi = (u16*)(w + 10 * MB);
  u16* Qlo = (u16*)((char*)Qhi + (size_t)nb * bs);
  u16* Khi = (u16*)((char*)Qhi + (size_t)2 * nb * bs);
  u16* Klo = (u16*)((char*)Qhi + (size_t)3 * nb * bs);
  u16* Vt = (u16*)((char*)Qhi + (size_t)4 * nb * bs);
  u16* P = (u16*)((char*)Qhi + (size_t)5 * nb * bs);  // 32 MB (64 if bigP)
  char* scb = (char*)P + (bigP ? 64 : 32) * MB;
  float* Sc = (float*)scb;
  u16* Xhi = (u16*)scb;
  u16* Xlo = Xhi + (size_t)nb * CS * CD;
  float* part = Sc;  // PV partials

  // score slab: full 4096 in the standard path; probe when ws is tiny.
  long slabQ = 4096;
  if (!big) {
    slabQ = 512;
    const size_t base = 82 * MB;  // nb=1: Sc starts at 82 MB
    for (long s = 4096; s >= 512; s >>= 1) {
      size_t region = (size_t)s * CS * 4;
      if (region < 16 * MB) region = 16 * MB;
      if (base + region <= ws_size) {
        slabQ = s;
        break;
      }
    }
  }

  // XCD 2D-chunk swizzle params (cw=4; ch = nwg/32), identity when invalid.
  auto pick = [](int gx, int gy, int& cw, int& ch) {
    cw = 0;
    ch = 0;
    const int nwg = gx * gy;
    if ((nwg & 31) || (gx & 3)) return;
    const int h = nwg >> 5;  // nwg/8/4
    if (h == 0 || (gy % h)) return;
    cw = 4;
    ch = h;
  };

  const dim3 blk(256);

  // weight prep (once per call): concatenated [3072,1024] hi / lo
  wtrans_split<<<dim3(32, 32), blk, 0, stream>>>(Wq, Whi, Wlo);
  wtrans_split<<<dim3(32, 32), blk, 0, stream>>>(Wk, Whi + 1024 * 1024,
                                                 Wlo + 1024 * 1024);
  wtrans_split<<<dim3(32, 32), blk, 0, stream>>>(Wv, Whi + 2 * 1024 * 1024,
                                                 nullptr);

  int cwqk, chqk, cwv, chv, cws, chs, cwp, chp, cwp2, chp2;
  pick(8, 16 * nb, cwqk, chqk);
  pick(4, 16 * nb, cwv, chv);
  pick(16, (int)(slabQ / 256) == 0 ? 1 : (int)(slabQ / 256), cws, chs);
  if (slabQ < 256) { cws = 0; chs = 0; }
  pick(4, 16, cwp, chp);
  pick(4, 32, cwp2, chp2);

  for (int g = 0; g < CB_; g += nb) {
    // stage X for batches g..g+nb-1
    split_f32<<<dim3(nb * CS * CD / 4 / 256), blk, 0, stream>>>(
        X + (long)g * CS * CD, Xhi, Xlo, nb * CS * CD / 4);

    // Q/K projection: uniform NT=48, grid (8, 16*nb)
    gemm256_qk<<<dim3(8, 16 * nb), dim3(512), 0, stream>>>(
        Xhi, Xlo, Whi, Wlo, Qhi, Qlo, Khi, Klo, cwqk, chqk);
    // V projection: NT=16, grid (4, 16*nb)
    gemm256_v<<<dim3(4, 16 * nb), dim3(512), 0, stream>>>(
        Xhi, Whi + 2 * 1024 * 1024, Vt, cwv, chv);

    for (int bb = 0; bb < nb; ++bb) {
      u16* Pb = P + (bigP ? (long)bb * CS * CS : 0);

      // scores + softmax
      for (long q0 = 0; q0 < CS; q0 += slabQ) {
        const long qo = (long)bb * CS * CA;
        const dim3 gs(CS / 256, (unsigned)(slabQ / 256));
        gemm256_nt<3><<<gs, dim3(512), 0, stream>>>(
            Qhi + qo + q0 * CA, Qlo + qo + q0 * CA, Qhi + qo + q0 * CA,
            Khi + qo, Khi + qo, Klo + qo, Sc, CA, CA, CA, CS, cws, chs);
        softmax_bf16<<<dim3((unsigned)slabQ), blk, 0, stream>>>(Sc,
                                                                Pb + q0 * CS);
      }
    }

    // out = P @ V
    if (bigP) {
      // both batches, split-K=2, one launch; partials [batch*2+z]
      gemm256_pv2<<<dim3(4, 32, 2), dim3(512), 0, stream>>>(P, Vt, part,
                                                            cwp2, chp2);
      for (int bb = 0; bb < nb; ++bb) {
        const long pl = (long)CS * CA;
        add2_f32<<<dim3(CS * CA / 4 / 256), blk, 0, stream>>>(
            part + (long)bb * 2 * pl, part + ((long)bb * 2 + 1) * pl,
            out + (long)(g + bb) * pl, CS * CA / 4);
      }
    } else {
      for (int bb = 0; bb < nb; ++bb) {
        float* outb = out + (long)(g + bb) * CS * CA;
        u16* Vtb = Vt + (long)bb * CA * CS;
        if (big) {
          gemm256_pv<<<dim3(4, 16, 4), dim3(512), 0, stream>>>(P, Vtb, part,
                                                               cwp, chp);
          add4_f32<<<dim3(CS * CA / 4 / 256), blk, 0, stream>>>(part, outb,
                                                                CS * CA / 4);
        } else {
          gemm_pv<4096><<<dim3(8, 32, 1), blk, 0, stream>>>(P, Vtb, outb);
        }
      }
    }
  }
}

// Round 7
// 917.240 us; speedup vs baseline: 1.0492x; 1.0492x over previous
//
#include <hip/hip_runtime.h>
#include <math.h>

// Problem: B=4, S=4096, D=1024, A=1024, fp32 in/out. No 1/sqrt(d) scaling.
// Strategy: split-bf16 (Ootomo) MFMA: C = Ahi@Bhi + Alo@Bhi + Ahi@Blo.
// All GEMMs NT (A row-major [M,K], B row-major [N,K]) so both operands
// stage via global_load_lds.
// R1: scores -> 256x256 8-phase counted-vmcnt kernel (98us, MfmaUtil 44%).
// R2: merged 128² QKV + splitK PV.  R3: all GEMMs on 8-phase 256².
// R4: uniform-NT qk/v split (qk 101us @44%).
// R5: XCD 2D swizzle (FETCH 203->74MB, dur UNCHANGED) -> schedule-internal.
// R6: ds_read prefetch under MFMA -> NULL. Read latency not the stall.
// R7 (this): faithful 2-K-tiles-per-iteration unroll (m201 template):
//   KITER256 takes a LITERAL buffer index -> compile-time LDS bases,
//   offset-folded ds_reads, no per-K-tile buf recompute or loop branch
//   per tile; MFMA cluster reordered kk-outer (bitwise identical).
constexpr int CS = 4096;
constexpr int CD = 1024;
constexpr int CA = 1024;
constexpr int CB_ = 4;

typedef unsigned short u16;
typedef __bf16 bf16x8 __attribute__((ext_vector_type(8)));
typedef float f32x4 __attribute__((ext_vector_type(4)));
typedef unsigned short u16x4 __attribute__((ext_vector_type(4)));

__device__ __forceinline__ u16 f32_to_bf16(float f) {
  unsigned u = __float_as_uint(f);
  u = (u + 0x7FFF + ((u >> 16) & 1)) >> 16;  // RNE
  return (u16)u;
}
__device__ __forceinline__ float bf16_to_f32(u16 h) {
  return __uint_as_float(((unsigned)h) << 16);
}

// async global->LDS, 16 B per lane; lds base MUST be wave-uniform.
__device__ __forceinline__ void async16(const u16* g, u16* lds_uniform) {
  __builtin_amdgcn_global_load_lds(
      (const __attribute__((address_space(1))) void*)g,
      (__attribute__((address_space(3))) void*)lds_uniform, 16, 0, 0);
}

// Bijective 2D-chunk XCD swizzle: XCD x (= lin%8) gets a cw x ch tile chunk.
// cw==0 -> identity. Requires GX%cw==0, (GX/cw)*(GY/ch)==8 (host-checked).
__device__ __forceinline__ void xcd_swz(int cw, int ch, int& bx, int& by) {
  if (cw == 0) return;
  const int GX = gridDim.x;
  const int lin = bx + GX * by;
  const int xcd = lin & 7, j = lin >> 3;
  const int ncx = GX / cw;
  bx = (xcd % ncx) * cw + (j % cw);
  by = (xcd / ncx) * ch + (j / cw);
}

// ---------------------------------------------------------------------------
// Shared 256x256 8-phase machinery (guide §5 256² template, plain HIP).
// 512 thr = 8 waves (2M x 4N), BK=64, 128 KiB LDS double-buffered,
// st_16x32 swizzle (inverse-swizzled global src + swizzled ds_read),
// counted vmcnt(6) (never 0 in main loop), s_setprio(1) around MFMA.
// LDS u16 layout: [buf:2][unit:4 = Blo,Bhi,Alo,Ahi][subtile:16][512].
// 2 K-tiles per loop iteration: BUF is a LITERAL (0/1) so LDS bases fold
// to compile-time constants. Per K-tile, 4 phases; A-frag reads for phase
// p+1 issued inside phase p's MFMA region (prefetch, sched_barrier-pinned).
// Macros reference per-kernel locals: lds, roA, roB, si0, lda, ldb, nbase,
// wr, wc, foff, acc, a1p, a2p, b2p.
// ---------------------------------------------------------------------------
#define ST_A256(BUF, AP, HALF)                                       \
  do {                                                               \
    const u16* _p = (AP) + roA + ((HALF) ? 128L * lda : 0L);         \
    u16* _d = &lds[(BUF)*32768 + (2 + (HALF)) * 8192 + si0 * 512];   \
    async16(_p, _d);                                                 \
    async16(_p + 32, _d + 512);                                      \
  } while (0)
#define ST_B256(BUF, BP, HALF)                                       \
  do {                                                               \
    const u16* _p = (BP) + roB + ((HALF) ? 128L * ldb : 0L);         \
    u16* _d = &lds[(BUF)*32768 + (HALF)*8192 + si0 * 512];           \
    async16(_p, _d);                                                 \
    async16(_p + 32, _d + 512);                                      \
  } while (0)

#define KITER256(BUF, DO_S1, DO_S2, VMW)                                      \
  do {                                                                        \
    const int bo_a = (BUF)*32768 + (2 + wr) * 8192;                           \
    const int bo_b = (BUF)*32768 + (wc >> 1) * 8192;                          \
    bf16x8 Bf[4][2], Am01[2][2], Am23[2][2], A47[4][2];                       \
    /* ---- phase 1: read all-B + A m0-1; stage (t+1).A-hi ---- */            \
    _Pragma("unroll") for (int n = 0; n < 4; ++n) _Pragma("unroll")           \
        for (int kk = 0; kk < 2; ++kk) Bf[n][kk] =                            \
        *(const bf16x8*)&lds[bo_b + ((nbase + n) * 2 + kk) * 512 + foff];     \
    _Pragma("unroll") for (int m = 0; m < 2; ++m) _Pragma("unroll")           \
        for (int kk = 0; kk < 2; ++kk) Am01[m][kk] =                          \
        *(const bf16x8*)&lds[bo_a + (m * 2 + kk) * 512 + foff];               \
    if (DO_S1) ST_A256((BUF) ^ 1, a1p, 1);                                    \
    __builtin_amdgcn_s_barrier();                                             \
    asm volatile("s_waitcnt lgkmcnt(0)" ::: "memory");                        \
    /* prefetch ph2's A m2-3 under MFMA1 */                                   \
    _Pragma("unroll") for (int m = 0; m < 2; ++m) _Pragma("unroll")           \
        for (int kk = 0; kk < 2; ++kk) Am23[m][kk] =                          \
        *(const bf16x8*)&lds[bo_a + ((2 + m) * 2 + kk) * 512 + foff];         \
    __builtin_amdgcn_sched_barrier(0);                                        \
    __builtin_amdgcn_s_setprio(1);                                            \
    _Pragma("unroll") for (int kk = 0; kk < 2; ++kk) _Pragma("unroll")        \
        for (int m = 0; m < 2; ++m) _Pragma("unroll")                         \
        for (int n = 0; n < 4; ++n) acc[m][n] =                               \
        __builtin_amdgcn_mfma_f32_16x16x32_bf16(Am01[m][kk], Bf[n][kk],       \
                                                acc[m][n], 0, 0, 0);          \
    __builtin_amdgcn_s_setprio(0);                                            \
    __builtin_amdgcn_s_barrier();                                             \
    /* ---- phase 2: stage (t+2).B-lo; MFMA m2-3 ---- */                      \
    if (DO_S2) ST_B256((BUF), b2p, 0);                                        \
    __builtin_amdgcn_s_barrier();                                             \
    asm volatile("s_waitcnt lgkmcnt(0)" ::: "memory");                        \
    /* prefetch ph3/4's A m4-7 under MFMA2 */                                 \
    _Pragma("unroll") for (int m = 0; m < 4; ++m) _Pragma("unroll")           \
        for (int kk = 0; kk < 2; ++kk) A47[m][kk] =                           \
        *(const bf16x8*)&lds[bo_a + ((4 + m) * 2 + kk) * 512 + foff];         \
    __builtin_amdgcn_sched_barrier(0);                                        \
    __builtin_amdgcn_s_setprio(1);                                            \
    _Pragma("unroll") for (int kk = 0; kk < 2; ++kk) _Pragma("unroll")        \
        for (int m = 0; m < 2; ++m) _Pragma("unroll")                         \
        for (int n = 0; n < 4; ++n) acc[2 + m][n] =                           \
        __builtin_amdgcn_mfma_f32_16x16x32_bf16(Am23[m][kk], Bf[n][kk],       \
                                                acc[2 + m][n], 0, 0, 0);      \
    __builtin_amdgcn_s_setprio(0);                                            \
    __builtin_amdgcn_s_barrier();                                             \
    /* ---- phase 3: stage (t+2).B-hi; MFMA m4-5 ---- */                      \
    if (DO_S2) ST_B256((BUF), b2p, 1);                                        \
    __builtin_amdgcn_s_barrier();                                             \
    asm volatile("s_waitcnt lgkmcnt(0)" ::: "memory");                        \
    __builtin_amdgcn_s_setprio(1);                                            \
    _Pragma("unroll") for (int kk = 0; kk < 2; ++kk) _Pragma("unroll")        \
        for (int m = 0; m < 2; ++m) _Pragma("unroll")                         \
        for (int n = 0; n < 4; ++n) acc[4 + m][n] =                           \
        __builtin_amdgcn_mfma_f32_16x16x32_bf16(A47[m][kk], Bf[n][kk],        \
                                                acc[4 + m][n], 0, 0, 0);      \
    __builtin_amdgcn_s_setprio(0);                                            \
    __builtin_amdgcn_s_barrier();                                             \
    /* ---- phase 4: stage (t+2).A-lo; MFMA m6-7; counted vmcnt ---- */       \
    if (DO_S2) ST_A256((BUF), a2p, 0);                                        \
    __builtin_amdgcn_s_barrier();                                             \
    asm volatile("s_waitcnt lgkmcnt(0)" ::: "memory");                        \
    __builtin_amdgcn_s_setprio(1);                                            \
    _Pragma("unroll") for (int kk = 0; kk < 2; ++kk) _Pragma("unroll")        \
        for (int m = 0; m < 2; ++m) _Pragma("unroll")                         \
        for (int n = 0; n < 4; ++n) acc[6 + m][n] =                           \
        __builtin_amdgcn_mfma_f32_16x16x32_bf16(A47[2 + m][kk], Bf[n][kk],    \
                                                acc[6 + m][n], 0, 0, 0);      \
    __builtin_amdgcn_s_setprio(0);                                            \
    VMW;                                                                      \
    __builtin_amdgcn_s_barrier();                                             \
  } while (0)

#define VM6 asm volatile("s_waitcnt vmcnt(6)" ::: "memory")
#define VM0 asm volatile("s_waitcnt vmcnt(0)" ::: "memory")

// ---------------------------------------------------------------------------
// Scores GEMM: generic NSEG-segmented NT, fp32 C out.
// ---------------------------------------------------------------------------
template <int NSEG>
__global__ __launch_bounds__(512, 2) void gemm256_nt(
    const u16* __restrict__ A0s, const u16* __restrict__ A1s,
    const u16* __restrict__ A2s, const u16* __restrict__ B0s,
    const u16* __restrict__ B1s, const u16* __restrict__ B2s,
    float* __restrict__ C, int Kd, int lda, int ldb, int ldc, int cw,
    int ch) {
  __shared__ u16 lds[65536];  // 128 KiB
  const int tid = threadIdx.x;
  const int wave = tid >> 6, lane = tid & 63;
  const int wr = wave >> 2, wc = wave & 3;       // wave -> 128x64 C sub-tile
  const int l16 = lane & 15, quad = lane >> 4;
  int bx = blockIdx.x, by = blockIdx.y;
  xcd_swz(cw, ch, bx, by);
  const int m0 = by * 256, n0 = bx * 256;
  const int foff = (l16 * 32 + quad * 8) ^ ((l16 & 8) << 1);
  const int si0 = wave * 2;
  const int srow = lane >> 2;                                  // subtile row
  const int scol = ((lane & 3) * 8) ^ ((lane & 32) ? 16 : 0);  // inv-swz col
  const long roA = (long)(m0 + wave * 16 + srow) * lda + scol;
  const long roB = (long)(n0 + wave * 16 + srow) * ldb + scol;
  const int nbase = (wc & 1) * 4;

  f32x4 acc[8][4];
#pragma unroll
  for (int i = 0; i < 8; ++i)
#pragma unroll
    for (int j = 0; j < 4; ++j) acc[i][j] = (f32x4){0.f, 0.f, 0.f, 0.f};

  const int ktps = Kd >> 6;       // K-tiles per segment
  const int NT = NSEG * ktps;     // total K-tiles (even)

  // cursor1 -> K-tile 1
  int s1 = 0, k1 = 64;
  if (k1 == Kd) { k1 = 0; s1 = 1; }
  const u16* a1p = (s1 == 0 ? A0s : A1s) + k1;
  const u16* b1p = (s1 == 0 ? B0s : B1s) + k1;
  // prologue: K-tile 0 {Blo,Bhi,Alo,Ahi}, K-tile 1 {Blo,Bhi,Alo}
  ST_B256(0, B0s, 0);
  ST_B256(0, B0s, 1);
  ST_A256(0, A0s, 0);
  ST_A256(0, A0s, 1);
  ST_B256(1, b1p, 0);
  ST_B256(1, b1p, 1);
  ST_A256(1, a1p, 0);
  (void)b1p;
  // cursor2 -> K-tile 2
  int s2 = s1, k2 = k1 + 64;
  if (k2 == Kd) { k2 = 0; ++s2; }
  const u16* a2p = (s2 == 0 ? A0s : (s2 == 1 ? A1s : A2s)) + k2;
  const u16* b2p = (s2 == 0 ? B0s : (s2 == 1 ? B1s : B2s)) + k2;
  VM6;  // K-tile 0 resident
  __builtin_amdgcn_s_barrier();

#define ADV_NT                                \
  do {                                        \
    a1p = a2p;                                \
    k2 += 64;                                 \
    if (k2 == Kd) {                           \
      k2 = 0;                                 \
      ++s2;                                   \
      a2p = (s2 == 1 ? A1s : A2s);            \
      b2p = (s2 == 1 ? B1s : B2s);            \
    } else {                                  \
      a2p += 64;                              \
      b2p += 64;                              \
    }                                         \
  } while (0)

  for (int t = 0; t + 3 < NT; t += 2) {
    KITER256(0, 1, 1, VM6);
    ADV_NT;
    KITER256(1, 1, 1, VM6);
    ADV_NT;
  }
  // tails: t = NT-2 (buf 0) stages only (NT-1).A-hi, drains; NT-1 pure.
  KITER256(0, 1, 0, VM0);
  KITER256(1, 0, 0, ((void)0));
#undef ADV_NT

  // epilogue: fp32 C. frag layout: col = lane&15, row = quad*4 + reg.
  const int rb0 = m0 + wr * 128 + quad * 4;
  const int cc0 = n0 + wc * 64 + l16;
#pragma unroll
  for (int m = 0; m < 8; ++m)
#pragma unroll
    for (int n = 0; n < 4; ++n) {
      const long rb = rb0 + m * 16;
      const int c = cc0 + n * 16;
#pragma unroll
      for (int r = 0; r < 4; ++r) C[(rb + r) * (long)ldc + c] = acc[m][n][r];
    }
}

// ---------------------------------------------------------------------------
// Q/K projection, UNIFORM NT=48 (3 segments). Region by n0>>10: 0=Q, 1=K;
// both split hi/lo out. Grid (8, 16*nb).
// ---------------------------------------------------------------------------
__global__ __launch_bounds__(512, 2) void gemm256_qk(
    const u16* __restrict__ Xhi, const u16* __restrict__ Xlo,
    const u16* __restrict__ Whi, const u16* __restrict__ Wlo,
    u16* __restrict__ Qhi, u16* __restrict__ Qlo, u16* __restrict__ Khi,
    u16* __restrict__ Klo, int cw, int ch) {
  __shared__ u16 lds[65536];
  const int tid = threadIdx.x;
  const int wave = tid >> 6, lane = tid & 63;
  const int wr = wave >> 2, wc = wave & 3;
  const int l16 = lane & 15, quad = lane >> 4;
  int bx = blockIdx.x, by = blockIdx.y;
  xcd_swz(cw, ch, bx, by);
  const int m0 = by * 256, n0 = bx * 256;
  const int region = n0 >> 10;  // 0=Q 1=K
  const int lda = CD, ldb = CD;
  const int foff = (l16 * 32 + quad * 8) ^ ((l16 & 8) << 1);
  const int si0 = wave * 2;
  const int srow = lane >> 2;
  const int scol = ((lane & 3) * 8) ^ ((lane & 32) ? 16 : 0);
  const long roA = (long)(m0 + wave * 16 + srow) * lda + scol;
  const long roB = (long)(n0 + wave * 16 + srow) * ldb + scol;
  const int nbase = (wc & 1) * 4;

  f32x4 acc[8][4];
#pragma unroll
  for (int i = 0; i < 8; ++i)
#pragma unroll
    for (int j = 0; j < 4; ++j) acc[i][j] = (f32x4){0.f, 0.f, 0.f, 0.f};

  const u16* Asegs[3] = {Xhi, Xlo, Xhi};
  const u16* Bsegs[3] = {Whi, Whi, Wlo};
  const int NT = 48;  // 3 segments x 16 K-tiles (Kd=1024, BK=64)

  const u16* a1p = Xhi + 64;
  int s2 = 0, k2 = 128;
  const u16* a2p = Xhi + 128;
  const u16* b2p = Whi + 128;
  ST_B256(0, Whi, 0);
  ST_B256(0, Whi, 1);
  ST_A256(0, Xhi, 0);
  ST_A256(0, Xhi, 1);
  ST_B256(1, Whi + 64, 0);
  ST_B256(1, Whi + 64, 1);
  ST_A256(1, Xhi + 64, 0);
  VM6;
  __builtin_amdgcn_s_barrier();

#define ADV_QK                                \
  do {                                        \
    a1p = a2p;                                \
    k2 += 64;                                 \
    if (k2 == CD) {                           \
      k2 = 0;                                 \
      ++s2;                                   \
      if (s2 < 3) {                           \
        a2p = Asegs[s2];                      \
        b2p = Bsegs[s2];                      \
      }                                       \
    } else {                                  \
      a2p += 64;                              \
      b2p += 64;                              \
    }                                         \
  } while (0)

  for (int t = 0; t + 3 < NT; t += 2) {
    KITER256(0, 1, 1, VM6);
    ADV_QK;
    KITER256(1, 1, 1, VM6);
    ADV_QK;
  }
  KITER256(0, 1, 0, VM0);
  KITER256(1, 0, 0, ((void)0));
#undef ADV_QK

  // epilogue: col = lane&15, row = quad*4 + reg (m89-verified mapping).
  const int rb0 = m0 + wr * 128 + quad * 4;
  const int ccl = (n0 & 1023) + wc * 64 + l16;
  u16* Chi = region ? Khi : Qhi;
  u16* Clo = region ? Klo : Qlo;
#pragma unroll
  for (int m = 0; m < 8; ++m)
#pragma unroll
    for (int n = 0; n < 4; ++n) {
      const long rb = rb0 + m * 16;
      const int c = ccl + n * 16;
#pragma unroll
      for (int r = 0; r < 4; ++r) {
        const float v = acc[m][n][r];
        const u16 h = f32_to_bf16(v);
        Chi[(rb + r) * (long)CA + c] = h;
        Clo[(rb + r) * (long)CA + c] = f32_to_bf16(v - bf16_to_f32(h));
      }
    }
}

// ---------------------------------------------------------------------------
// V projection, NT=16 (NSEG=1). Transposed bf16 out: Vt[batch][a][s].
// Grid (4, 16*nb).
// ---------------------------------------------------------------------------
__global__ __launch_bounds__(512, 2) void gemm256_v(
    const u16* __restrict__ Xhi, const u16* __restrict__ Wvhi,
    u16* __restrict__ Vt, int cw, int ch) {
  __shared__ u16 lds[65536];
  const int tid = threadIdx.x;
  const int wave = tid >> 6, lane = tid & 63;
  const int wr = wave >> 2, wc = wave & 3;
  const int l16 = lane & 15, quad = lane >> 4;
  int bx = blockIdx.x, by = blockIdx.y;
  xcd_swz(cw, ch, bx, by);
  const int m0 = by * 256, n0 = bx * 256;
  const int lda = CD, ldb = CD;
  const int foff = (l16 * 32 + quad * 8) ^ ((l16 & 8) << 1);
  const int si0 = wave * 2;
  const int srow = lane >> 2;
  const int scol = ((lane & 3) * 8) ^ ((lane & 32) ? 16 : 0);
  const long roA = (long)(m0 + wave * 16 + srow) * lda + scol;
  const long roB = (long)(n0 + wave * 16 + srow) * ldb + scol;
  const int nbase = (wc & 1) * 4;

  f32x4 acc[8][4];
#pragma unroll
  for (int i = 0; i < 8; ++i)
#pragma unroll
    for (int j = 0; j < 4; ++j) acc[i][j] = (f32x4){0.f, 0.f, 0.f, 0.f};

  const int NT = 16;
  const u16* a1p = Xhi + 64;
  const u16* a2p = Xhi + 128;
  const u16* b2p = Wvhi + 128;
  ST_B256(0, Wvhi, 0);
  ST_B256(0, Wvhi, 1);
  ST_A256(0, Xhi, 0);
  ST_A256(0, Xhi, 1);
  ST_B256(1, Wvhi + 64, 0);
  ST_B256(1, Wvhi + 64, 1);
  ST_A256(1, Xhi + 64, 0);
  VM6;
  __builtin_amdgcn_s_barrier();

  for (int t = 0; t + 3 < NT; t += 2) {
    KITER256(0, 1, 1, VM6);
    a1p = a2p; a2p += 64; b2p += 64;
    KITER256(1, 1, 1, VM6);
    a1p = a2p; a2p += 64; b2p += 64;
  }
  KITER256(0, 1, 0, VM0);
  KITER256(1, 0, 0, ((void)0));

  // epilogue: transposed bf16 per batch: Vt[batch][a][s].
  const int rb0 = m0 + wr * 128 + quad * 4;
  const int ccl = n0 + wc * 64 + l16;
#pragma unroll
  for (int m = 0; m < 8; ++m) {
    const int rg = rb0 + m * 16;
    const long vb = (long)(rg >> 12) * CA * CS;
    const int s = rg & 4095;
#pragma unroll
    for (int n = 0; n < 4; ++n) {
      const int c = ccl + n * 16;
      u16x4 p;
#pragma unroll
      for (int r = 0; r < 4; ++r) p[r] = f32_to_bf16(acc[m][n][r]);
      *(u16x4*)&Vt[vb + (long)c * CS + s] = p;
    }
  }
}

// ---------------------------------------------------------------------------
// PV split-K=4 (single batch). Grid (4,16,4). Partials Cp + z*CS*CA.
// ---------------------------------------------------------------------------
__global__ __launch_bounds__(512, 2) void gemm256_pv(
    const u16* __restrict__ P, const u16* __restrict__ Vtb,
    float* __restrict__ Cp, int cw, int ch) {
  __shared__ u16 lds[65536];
  const int tid = threadIdx.x;
  const int wave = tid >> 6, lane = tid & 63;
  const int wr = wave >> 2, wc = wave & 3;
  const int l16 = lane & 15, quad = lane >> 4;
  int bx = blockIdx.x, by = blockIdx.y;
  xcd_swz(cw, ch, bx, by);
  const int m0 = by * 256, n0 = bx * 256;
  const int z = blockIdx.z;
  const int lda = CS, ldb = CS;
  const int foff = (l16 * 32 + quad * 8) ^ ((l16 & 8) << 1);
  const int si0 = wave * 2;
  const int srow = lane >> 2;
  const int scol = ((lane & 3) * 8) ^ ((lane & 32) ? 16 : 0);
  const long roA = (long)(m0 + wave * 16 + srow) * lda + scol;
  const long roB = (long)(n0 + wave * 16 + srow) * ldb + scol;
  const int nbase = (wc & 1) * 4;

  f32x4 acc[8][4];
#pragma unroll
  for (int i = 0; i < 8; ++i)
#pragma unroll
    for (int j = 0; j < 4; ++j) acc[i][j] = (f32x4){0.f, 0.f, 0.f, 0.f};

  const u16* A0 = P + (long)z * 1024;
  const u16* B0 = Vtb + (long)z * 1024;
  const int NT = 16;
  const u16* a1p = A0 + 64;
  const u16* a2p = A0 + 128;
  const u16* b2p = B0 + 128;
  ST_B256(0, B0, 0);
  ST_B256(0, B0, 1);
  ST_A256(0, A0, 0);
  ST_A256(0, A0, 1);
  ST_B256(1, B0 + 64, 0);
  ST_B256(1, B0 + 64, 1);
  ST_A256(1, A0 + 64, 0);
  VM6;
  __builtin_amdgcn_s_barrier();

  for (int t = 0; t + 3 < NT; t += 2) {
    KITER256(0, 1, 1, VM6);
    a1p = a2p; a2p += 64; b2p += 64;
    KITER256(1, 1, 1, VM6);
    a1p = a2p; a2p += 64; b2p += 64;
  }
  KITER256(0, 1, 0, VM0);
  KITER256(1, 0, 0, ((void)0));

  float* C = Cp + (long)z * CS * CA;
  const int rb0 = m0 + wr * 128 + quad * 4;
  const int cc0 = n0 + wc * 64 + l16;
#pragma unroll
  for (int m = 0; m < 8; ++m)
#pragma unroll
    for (int n = 0; n < 4; ++n) {
      const long rb = rb0 + m * 16;
      const int c = cc0 + n * 16;
#pragma unroll
      for (int r = 0; r < 4; ++r) C[(rb + r) * (long)CA + c] = acc[m][n][r];
    }
}

// ---------------------------------------------------------------------------
// Batched PV: 2 batches x split-K=2, NT=32. Grid (4, 32, 2) = 256 blocks.
// P2 = 2 contiguous [CS,CS] bf16 planes; Vt = 2 x [CA,CS]; partials
// Cp[batch*2 + z][CS,CA] fp32. Block row-range never crosses a batch.
// ---------------------------------------------------------------------------
__global__ __launch_bounds__(512, 2) void gemm256_pv2(
    const u16* __restrict__ P2, const u16* __restrict__ Vt,
    float* __restrict__ Cp, int cw, int ch) {
  __shared__ u16 lds[65536];
  const int tid = threadIdx.x;
  const int wave = tid >> 6, lane = tid & 63;
  const int wr = wave >> 2, wc = wave & 3;
  const int l16 = lane & 15, quad = lane >> 4;
  int bx = blockIdx.x, by = blockIdx.y;
  xcd_swz(cw, ch, bx, by);
  const int z = blockIdx.z;
  const int batch = by >> 4;
  const int m0 = (by & 15) * 256, n0 = bx * 256;
  const int lda = CS, ldb = CS;
  const int foff = (l16 * 32 + quad * 8) ^ ((l16 & 8) << 1);
  const int si0 = wave * 2;
  const int srow = lane >> 2;
  const int scol = ((lane & 3) * 8) ^ ((lane & 32) ? 16 : 0);
  const long roA = (long)(m0 + wave * 16 + srow) * lda + scol;
  const long roB = (long)(n0 + wave * 16 + srow) * ldb + scol;
  const int nbase = (wc & 1) * 4;

  f32x4 acc[8][4];
#pragma unroll
  for (int i = 0; i < 8; ++i)
#pragma unroll
    for (int j = 0; j < 4; ++j) acc[i][j] = (f32x4){0.f, 0.f, 0.f, 0.f};

  const u16* A0 = P2 + (long)batch * CS * CS + (long)z * 2048;
  const u16* B0 = Vt + (long)batch * CA * CS + (long)z * 2048;
  const int NT = 32;  // K = 2048 per z
  const u16* a1p = A0 + 64;
  const u16* a2p = A0 + 128;
  const u16* b2p = B0 + 128;
  ST_B256(0, B0, 0);
  ST_B256(0, B0, 1);
  ST_A256(0, A0, 0);
  ST_A256(0, A0, 1);
  ST_B256(1, B0 + 64, 0);
  ST_B256(1, B0 + 64, 1);
  ST_A256(1, A0 + 64, 0);
  VM6;
  __builtin_amdgcn_s_barrier();

  for (int t = 0; t + 3 < NT; t += 2) {
    KITER256(0, 1, 1, VM6);
    a1p = a2p; a2p += 64; b2p += 64;
    KITER256(1, 1, 1, VM6);
    a1p = a2p; a2p += 64; b2p += 64;
  }
  KITER256(0, 1, 0, VM0);
  KITER256(1, 0, 0, ((void)0));

  float* C = Cp + ((long)batch * 2 + z) * CS * CA;
  const int rb0 = m0 + wr * 128 + quad * 4;
  const int cc0 = n0 + wc * 64 + l16;
#pragma unroll
  for (int m = 0; m < 8; ++m)
#pragma unroll
    for (int n = 0; n < 4; ++n) {
      const long rb = rb0 + m * 16;
      const int c = cc0 + n * 16;
#pragma unroll
      for (int r = 0; r < 4; ++r) C[(rb + r) * (long)CA + c] = acc[m][n][r];
    }
}

#undef KITER256
#undef ST_A256
#undef ST_B256
#undef VM6
#undef VM0

// ---------------------------------------------------------------------------
// Legacy 128² PV (tiny-ws fallback only): direct full-K into C.
// ---------------------------------------------------------------------------
template <int KD>
__global__ __launch_bounds__(256) void gemm_pv(const u16* __restrict__ P,
                                               const u16* __restrict__ Vtb,
                                               float* __restrict__ Cp) {
  __shared__ u16 As[128 * 32];
  __shared__ u16 Bs[128 * 32];
  const int tid = threadIdx.x;
  const int wave = tid >> 6, lane = tid & 63;
  const int quad = lane >> 4, l16 = lane & 15;
  const int m0 = blockIdx.y * 128, n0 = blockIdx.x * 128;
  const int z = blockIdx.z;
  const int wm = (wave >> 1) * 64, wn = (wave & 1) * 64;
  const int srow = lane >> 2;
  const int scol = (lane & 3) * 8;
  const int c0 = wave, c1 = wave + 4;

  const u16* Ab = P + (long)m0 * CS + (long)z * KD;
  const u16* Bb = Vtb + (long)n0 * CS + (long)z * KD;
  float* C = Cp + (long)z * CS * CA;

  f32x4 acc[4][4];
#pragma unroll
  for (int i = 0; i < 4; ++i)
#pragma unroll
    for (int j = 0; j < 4; ++j) acc[i][j] = (f32x4){0.f, 0.f, 0.f, 0.f};

  for (int k0 = 0; k0 < KD; k0 += 32) {
    async16(Ab + (long)(c0 * 16 + srow) * CS + k0 + scol, As + c0 * 512);
    async16(Ab + (long)(c1 * 16 + srow) * CS + k0 + scol, As + c1 * 512);
    async16(Bb + (long)(c0 * 16 + srow) * CS + k0 + scol, Bs + c0 * 512);
    async16(Bb + (long)(c1 * 16 + srow) * CS + k0 + scol, Bs + c1 * 512);
    __syncthreads();
    bf16x8 af[4], bfr[4];
#pragma unroll
    for (int i = 0; i < 4; ++i)
      af[i] = *(const bf16x8*)&As[(wm + i * 16 + l16) * 32 + quad * 8];
#pragma unroll
    for (int j = 0; j < 4; ++j)
      bfr[j] = *(const bf16x8*)&Bs[(wn + j * 16 + l16) * 32 + quad * 8];
#pragma unroll
    for (int i = 0; i < 4; ++i)
#pragma unroll
      for (int j = 0; j < 4; ++j)
        acc[i][j] = __builtin_amdgcn_mfma_f32_16x16x32_bf16(af[i], bfr[j],
                                                            acc[i][j], 0, 0, 0);
    __syncthreads();
  }

#pragma unroll
  for (int i = 0; i < 4; ++i) {
    const int rb = m0 + wm + i * 16 + quad * 4;
#pragma unroll
    for (int j = 0; j < 4; ++j) {
      const int c = n0 + wn + j * 16 + l16;
#pragma unroll
      for (int r = 0; r < 4; ++r) C[(long)(rb + r) * CA + c] = acc[i][j][r];
    }
  }
}

// o = p0+p1+p2+p3 (stride CS*CA floats), float4-vectorized.
__global__ __launch_bounds__(256) void add4_f32(const float* __restrict__ p,
                                                float* __restrict__ o, int n4) {
  const int idx = blockIdx.x * 256 + threadIdx.x;
  if (idx >= n4) return;
  const long st = (long)CS * CA / 4;
  const float4 a = ((const float4*)p)[idx];
  const float4 b = ((const float4*)p)[idx + st];
  const float4 c = ((const float4*)p)[idx + 2 * st];
  const float4 d = ((const float4*)p)[idx + 3 * st];
  float4 r;
  r.x = (a.x + b.x) + (c.x + d.x);
  r.y = (a.y + b.y) + (c.y + d.y);
  r.z = (a.z + b.z) + (c.z + d.z);
  r.w = (a.w + b.w) + (c.w + d.w);
  ((float4*)o)[idx] = r;
}

// o = a + b, float4-vectorized.
__global__ __launch_bounds__(256) void add2_f32(const float* __restrict__ a,
                                                const float* __restrict__ b,
                                                float* __restrict__ o, int n4) {
  const int idx = blockIdx.x * 256 + threadIdx.x;
  if (idx >= n4) return;
  const float4 x = ((const float4*)a)[idx];
  const float4 y = ((const float4*)b)[idx];
  float4 r;
  r.x = x.x + y.x;
  r.y = x.y + y.y;
  r.z = x.z + y.z;
  r.w = x.w + y.w;
  ((float4*)o)[idx] = r;
}

// ---------------------------------------------------------------------------
// W [D,A] fp32 -> Wt hi/lo bf16 [A,D] (transposed). Tlo may be null.
// ---------------------------------------------------------------------------
__global__ __launch_bounds__(256) void wtrans_split(const float* __restrict__ W,
                                                    u16* __restrict__ Thi,
                                                    u16* __restrict__ Tlo) {
  __shared__ float t[32][33];
  const int tx = threadIdx.x & 31, ty = threadIdx.x >> 5;
  const int a0 = blockIdx.x * 32;  // col tile of W (a)
  const int d0 = blockIdx.y * 32;  // row tile of W (d)
#pragma unroll
  for (int i = 0; i < 32; i += 8)
    t[ty + i][tx] = W[(long)(d0 + ty + i) * CA + a0 + tx];
  __syncthreads();
#pragma unroll
  for (int i = 0; i < 32; i += 8) {
    const float v = t[tx][ty + i];  // = W[d0+tx][a0+ty+i]
    const int a = a0 + ty + i, d = d0 + tx;
    const u16 h = f32_to_bf16(v);
    Thi[(long)a * CD + d] = h;
    if (Tlo) Tlo[(long)a * CD + d] = f32_to_bf16(v - bf16_to_f32(h));
  }
}

// fp32 -> (hi, lo) bf16, elementwise, float4-vectorized.
__global__ __launch_bounds__(256) void split_f32(const float* __restrict__ X,
                                                 u16* __restrict__ hi,
                                                 u16* __restrict__ lo, int n4) {
  const int idx = blockIdx.x * 256 + threadIdx.x;
  if (idx >= n4) return;
  const float4 v = ((const float4*)X)[idx];
  u16x4 h, l;
  const float vv[4] = {v.x, v.y, v.z, v.w};
#pragma unroll
  for (int i = 0; i < 4; ++i) {
    h[i] = f32_to_bf16(vv[i]);
    l[i] = f32_to_bf16(vv[i] - bf16_to_f32(h[i]));
  }
  ((u16x4*)hi)[idx] = h;
  ((u16x4*)lo)[idx] = l;
}

// ---------------------------------------------------------------------------
// Row softmax over 4096-wide rows (fp32 in, bf16 out), one block per row,
// float4 loads / u16x4 stores.
// ---------------------------------------------------------------------------
__global__ __launch_bounds__(256) void softmax_bf16(const float* __restrict__ Sc,
                                                    u16* __restrict__ P) {
  const long row = blockIdx.x;
  const float4* p4 = (const float4*)(Sc + row * 4096L);
  u16x4* q4 = (u16x4*)(P + row * 4096L);
  const int tid = threadIdx.x;

  float4 v[4];
#pragma unroll
  for (int i = 0; i < 4; ++i) v[i] = p4[tid + (i << 8)];
  float r[16];
#pragma unroll
  for (int i = 0; i < 4; ++i) {
    r[4 * i] = v[i].x;
    r[4 * i + 1] = v[i].y;
    r[4 * i + 2] = v[i].z;
    r[4 * i + 3] = v[i].w;
  }

  float m = r[0];
#pragma unroll
  for (int i = 1; i < 16; ++i) m = fmaxf(m, r[i]);
#pragma unroll
  for (int off = 32; off > 0; off >>= 1) m = fmaxf(m, __shfl_down(m, off));

  __shared__ float smax[4];
  __shared__ float ssum[4];
  const int lane = tid & 63;
  const int wv = tid >> 6;
  if (lane == 0) smax[wv] = m;
  __syncthreads();
  m = fmaxf(fmaxf(smax[0], smax[1]), fmaxf(smax[2], smax[3]));

  float s = 0.f;
#pragma unroll
  for (int i = 0; i < 16; ++i) {
    r[i] = __expf(r[i] - m);
    s += r[i];
  }
#pragma unroll
  for (int off = 32; off > 0; off >>= 1) s += __shfl_down(s, off);
  if (lane == 0) ssum[wv] = s;
  __syncthreads();
  s = (ssum[0] + ssum[1]) + (ssum[2] + ssum[3]);

  const float inv = 1.0f / s;
#pragma unroll
  for (int i = 0; i < 4; ++i) {
    u16x4 h;
#pragma unroll
    for (int k = 0; k < 4; ++k) h[k] = f32_to_bf16(r[4 * i + k] * inv);
    q4[tid + (i << 8)] = h;
  }
}

// ---------------------------------------------------------------------------
// Workspace layout (byte offsets), batch-group size nb in {4,2,1}:
//  0: Whi [3072,1024] (6 MB), 6: Wlo (Q|K rows, 4 MB)     [resident]
// 10: Qhi/Qlo/Khi/Klo (each 8*nb) , Vt (8*nb)  -> [10, 10+40nb)
// 10+40nb: P (32 MB; 64 MB when bigP: both batches)
// then: Sc (64 MB fp32) ALIASED with X staging and PV partials.
// need: nb=1 -> 146 (proven R1), nb=2 -> 186 (proven R3), nb=2+bigP -> 218
// (proven R5), nb=4 -> 266. Gated on ws_size.
// ---------------------------------------------------------------------------
extern "C" void kernel_launch(void* const* d_in, const int* in_sizes, int n_in,
                              void* d_out, int out_size, void* d_ws,
                              size_t ws_size, hipStream_t stream) {
  const float* X = (const float*)d_in[0];
  const float* Wq = (const float*)d_in[1];
  const float* Wk = (const float*)d_in[2];
  const float* Wv = (const float*)d_in[3];
  float* out = (float*)d_out;

  const size_t MB = 1 << 20;
  char* w = (char*)d_ws;
  u16* Whi = (u16*)(w + 0 * MB);  // [3072,1024] Q|K|V hi
  u16* Wlo = (u16*)(w + 6 * MB);  // [2048,1024] Q|K lo

  int nb = 1;
  if (ws_size >= 266 * MB) nb = 4;
  else if (ws_size >= 186 * MB) nb = 2;
  const bool big = ws_size >= 146 * MB;
  if (!big) nb = 1;
  const bool bigP = (nb == 2) && (ws_size >= 218 * MB);  // batched PV path

  const size_t bs = (size_t)CS * CA * 2;  // 8 MB: one bf16 [4096,1024] plane
  u16* Qhi = (u16*)(w + 10 * MB);
  u16* Qlo = (u16*)((char*)Qhi + (size_t)nb * bs);
  u16* Khi = (u16*)((char*)Qhi + (size_t)2 * nb * bs);
  u16* Klo = (u16*)((char*)Qhi + (size_t)3 * nb * bs);
  u16* Vt = (u16*)((char*)Qhi + (size_t)4 * nb * bs);
  u16* P = (u16*)((char*)Qhi + (size_t)5 * nb * bs);  // 32 MB (64 if bigP)
  char* scb = (char*)P + (bigP ? 64 : 32) * MB;
  float* Sc = (float*)scb;
  u16* Xhi = (u16*)scb;
  u16* Xlo = Xhi + (size_t)nb * CS * CD;
  float* part = Sc;  // PV partials

  // score slab: full 4096 in the standard path; probe when ws is tiny.
  long slabQ = 4096;
  if (!big) {
    slabQ = 512;
    const size_t base = 82 * MB;  // nb=1: Sc starts at 82 MB
    for (long s = 4096; s >= 512; s >>= 1) {
      size_t region = (size_t)s * CS * 4;
      if (region < 16 * MB) region = 16 * MB;
      if (base + region <= ws_size) {
        slabQ = s;
        break;
      }
    }
  }

  // XCD 2D-chunk swizzle params (cw=4; ch = nwg/32), identity when invalid.
  auto pick = [](int gx, int gy, int& cw, int& ch) {
    cw = 0;
    ch = 0;
    const int nwg = gx * gy;
    if ((nwg & 31) || (gx & 3)) return;
    const int h = nwg >> 5;  // nwg/8/4
    if (h == 0 || (gy % h)) return;
    cw = 4;
    ch = h;
  };

  const dim3 blk(256);

  // weight prep (once per call): concatenated [3072,1024] hi / lo
  wtrans_split<<<dim3(32, 32), blk, 0, stream>>>(Wq, Whi, Wlo);
  wtrans_split<<<dim3(32, 32), blk, 0, stream>>>(Wk, Whi + 1024 * 1024,
                                                 Wlo + 1024 * 1024);
  wtrans_split<<<dim3(32, 32), blk, 0, stream>>>(Wv, Whi + 2 * 1024 * 1024,
                                                 nullptr);

  int cwqk, chqk, cwv, chv, cws, chs, cwp, chp, cwp2, chp2;
  pick(8, 16 * nb, cwqk, chqk);
  pick(4, 16 * nb, cwv, chv);
  pick(16, (int)(slabQ / 256) == 0 ? 1 : (int)(slabQ / 256), cws, chs);
  if (slabQ < 256) { cws = 0; chs = 0; }
  pick(4, 16, cwp, chp);
  pick(4, 32, cwp2, chp2);

  for (int g = 0; g < CB_; g += nb) {
    // stage X for batches g..g+nb-1
    split_f32<<<dim3(nb * CS * CD / 4 / 256), blk, 0, stream>>>(
        X + (long)g * CS * CD, Xhi, Xlo, nb * CS * CD / 4);

    // Q/K projection: uniform NT=48, grid (8, 16*nb)
    gemm256_qk<<<dim3(8, 16 * nb), dim3(512), 0, stream>>>(
        Xhi, Xlo, Whi, Wlo, Qhi, Qlo, Khi, Klo, cwqk, chqk);
    // V projection: NT=16, grid (4, 16*nb)
    gemm256_v<<<dim3(4, 16 * nb), dim3(512), 0, stream>>>(
        Xhi, Whi + 2 * 1024 * 1024, Vt, cwv, chv);

    for (int bb = 0; bb < nb; ++bb) {
      u16* Pb = P + (bigP ? (long)bb * CS * CS : 0);

      // scores + softmax
      for (long q0 = 0; q0 < CS; q0 += slabQ) {
        const long qo = (long)bb * CS * CA;
        const dim3 gs(CS / 256, (unsigned)(slabQ / 256));
        gemm256_nt<3><<<gs, dim3(512), 0, stream>>>(
            Qhi + qo + q0 * CA, Qlo + qo + q0 * CA, Qhi + qo + q0 * CA,
            Khi + qo, Khi + qo, Klo + qo, Sc, CA, CA, CA, CS, cws, chs);
        softmax_bf16<<<dim3((unsigned)slabQ), blk, 0, stream>>>(Sc,
                                                                Pb + q0 * CS);
      }
    }

    // out = P @ V
    if (bigP) {
      // both batches, split-K=2, one launch; partials [batch*2+z]
      gemm256_pv2<<<dim3(4, 32, 2), dim3(512), 0, stream>>>(P, Vt, part,
                                                            cwp2, chp2);
      for (int bb = 0; bb < nb; ++bb) {
        const long pl = (long)CS * CA;
        add2_f32<<<dim3(CS * CA / 4 / 256), blk, 0, stream>>>(
            part + (long)bb * 2 * pl, part + ((long)bb * 2 + 1) * pl,
            out + (long)(g + bb) * pl, CS * CA / 4);
      }
    } else {
      for (int bb = 0; bb < nb; ++bb) {
        float* outb = out + (long)(g + bb) * CS * CA;
        u16* Vtb = Vt + (long)bb * CA * CS;
        if (big) {
          gemm256_pv<<<dim3(4, 16, 4), dim3(512), 0, stream>>>(P, Vtb, part,
                                                               cwp, chp);
          add4_f32<<<dim3(CS * CA / 4 / 256), blk, 0, stream>>>(part, outb,
                                                                CS * CA / 4);
        } else {
          gemm_pv<4096><<<dim3(8, 32, 1), blk, 0, stream>>>(P, Vtb, outb);
        }
      }
    }
  }
}